// Round 14
// baseline (1033.554 us; speedup 1.0000x reference)
//
#include <hip/hip_runtime.h>

typedef unsigned short u16;
typedef unsigned int   u32;
typedef unsigned long long u64;
typedef __attribute__((ext_vector_type(8))) short short8;
typedef __attribute__((ext_vector_type(4))) float f32x4;

#define NNODES 20000
#define MPAD   20096          // 157*128
#define DIN    512
#define HID    256
#define NCLS   7
#define NLAY   2
#define NEDGE  131072
#define NPAIR  8192
#define BN_EPS 1e-5f

__device__ __forceinline__ void atomAddF(float* p, float v) { unsafeAtomicAdd(p, v); }

__device__ __forceinline__ float b2f(u16 u) {
    u32 x = ((u32)u) << 16;
    return __builtin_bit_cast(float, x);
}
__device__ __forceinline__ u16 f2b(float f) {
    u32 u = __builtin_bit_cast(u32, f);
    u32 r = u + 0x7FFFu + ((u >> 16) & 1u);
    return (u16)(r >> 16);
}
__device__ __forceinline__ float4 b2f4(ushort4 u) {
    return make_float4(b2f(u.x), b2f(u.y), b2f(u.z), b2f(u.w));
}
__device__ __forceinline__ ushort4 f2b4(float a, float b, float c, float d) {
    ushort4 o; o.x = f2b(a); o.y = f2b(b); o.z = f2b(c); o.w = f2b(d); return o;
}

__device__ __forceinline__ void async_copy16(const u16* g, u16* l) {
    __builtin_amdgcn_global_load_lds((const __attribute__((address_space(1))) void*)g,
                                     (__attribute__((address_space(3))) void*)l, 16, 0, 0);
}

// bijective chunk swizzle (m204 form)
__device__ __forceinline__ int chunk_swz(int orig, int nwg) {
    int xcd = orig & 7, q = nwg >> 3, r = nwg & 7;
    int base = (xcd < r) ? xcd * (q + 1) : r * (q + 1) + (xcd - r) * q;
    return base + (orig >> 3);
}

// ---------------------------------------------------------------------------
// Full-N bf16 MFMA GEMM (N<=256): per z: C = A[z] @ Bt[z]^T (+bias)(opt relu)
// statsOut: accumulate per-column sum/sumsq of (acc+bias) pre-relu (BatchNorm)
// ---------------------------------------------------------------------------
__global__ __launch_bounds__(256, 2) void gemm_fn(
    const u16* __restrict__ A, size_t sA, const u16* __restrict__ Bt, size_t sB,
    const float* __restrict__ bias, int sBias,
    float* __restrict__ Cf, u16* __restrict__ Cb, size_t sC,
    int M, int N, int K, int relu, float* statsOut)
{
    const int z = blockIdx.z;
    A  += (size_t)z * sA;
    Bt += (size_t)z * sB;
    if (bias) bias += (size_t)z * sBias;

    __shared__ u16 sm[12288];
    __shared__ float sred[512];
    u16* As = sm;
    u16* Bs = sm + 4096;

    const int tid  = threadIdx.x;
    const int wave = tid >> 6;
    const int lane = tid & 63;
    const int bm = blockIdx.x * 128;
    const int wr = (wave >> 1) * 64;
    const int wc = (wave & 1) * 128;

    const int ar = tid >> 2, aj = (tid & 3) * 8;
    const u16* AgA = A + (size_t)(bm + ar) * K + aj;
    const u16* AgB = A + (size_t)(bm + ar + 64) * K + aj;
    u16* AsA = As + tid * 8;
    u16* AsB = As + tid * 8 + 2048;
    const u16* BgC[4]; u16* BsC[4];
    #pragma unroll
    for (int c = 0; c < 4; ++c) {
        BgC[c] = Bt + (size_t)(c * 64 + ar) * K + aj;
        BsC[c] = Bs + ((size_t)c * 256 + tid) * 8;
    }

    const int fr = lane & 15;
    const int fq = lane >> 4;
    const int kg = fq * 8;

    f32x4 zero = {0.f, 0.f, 0.f, 0.f};
    f32x4 acc[4][8];
    #pragma unroll
    for (int mi = 0; mi < 4; ++mi)
        #pragma unroll
        for (int ni = 0; ni < 8; ++ni) acc[mi][ni] = zero;

    for (int k0 = 0; k0 < K; k0 += 32) {
        async_copy16(AgA + k0, AsA);
        async_copy16(AgB + k0, AsB);
        #pragma unroll
        for (int c = 0; c < 4; ++c) async_copy16(BgC[c] + k0, BsC[c]);
        __syncthreads();
        short8 af[4], bfr[8];
        #pragma unroll
        for (int mi = 0; mi < 4; ++mi)
            af[mi] = *(const short8*)&As[(wr + mi * 16 + fr) * 32 + kg];
        #pragma unroll
        for (int ni = 0; ni < 8; ++ni)
            bfr[ni] = *(const short8*)&Bs[(wc + ni * 16 + fr) * 32 + kg];
        #pragma unroll
        for (int mi = 0; mi < 4; ++mi)
            #pragma unroll
            for (int ni = 0; ni < 8; ++ni)
                acc[mi][ni] = __builtin_amdgcn_mfma_f32_16x16x32_bf16(
                    af[mi], bfr[ni], acc[mi][ni], 0, 0, 0);
        __syncthreads();
    }

    float bv[8];
    #pragma unroll
    for (int ni = 0; ni < 8; ++ni) {
        int col = wc + ni * 16 + fr;
        bv[ni] = (bias && col < N) ? bias[col] : 0.f;
    }

    if (statsOut) {
        sred[tid] = 0.f; sred[256 + tid] = 0.f;
        __syncthreads();
        #pragma unroll
        for (int ni = 0; ni < 8; ++ni) {
            int col = wc + ni * 16 + fr;
            float s = 0.f, sq = 0.f;
            #pragma unroll
            for (int mi = 0; mi < 4; ++mi)
                #pragma unroll
                for (int rr = 0; rr < 4; ++rr) {
                    int row = bm + wr + mi * 16 + fq * 4 + rr;
                    if (row < M) {
                        float v = acc[mi][ni][rr] + bv[ni];
                        s += v; sq += v * v;
                    }
                }
            atomicAdd(&sred[col], s);
            atomicAdd(&sred[256 + col], sq);
        }
        __syncthreads();
        atomAddF(&statsOut[(size_t)z * 512 + tid], sred[tid]);
        atomAddF(&statsOut[(size_t)z * 512 + 256 + tid], sred[256 + tid]);
    }

    if (Cb && N == 256) {
        u16* R = sm;
        const int lrb = (wave >> 1) * 16 + fq * 4;
        const int cb0 = wc + fr;
        #pragma unroll
        for (int mi = 0; mi < 4; ++mi) {
            __syncthreads();
            #pragma unroll
            for (int ni = 0; ni < 8; ++ni)
                #pragma unroll
                for (int rr = 0; rr < 4; ++rr) {
                    float v = acc[mi][ni][rr] + bv[ni];
                    if (relu) v = fmaxf(v, 0.f);
                    R[(lrb + rr) * 264 + cb0 + ni * 16] = f2b(v);
                }
            __syncthreads();
            #pragma unroll
            for (int p = 0; p < 4; ++p) {
                int idx = p * 256 + tid;
                int lr = idx >> 5, ch = idx & 31;
                int grow = bm + (lr >> 4) * 64 + mi * 16 + (lr & 15);
                if (grow < M)
                    *(short8*)&Cb[(size_t)z * sC + (size_t)grow * 256 + ch * 8] =
                        *(const short8*)&R[lr * 264 + ch * 8];
            }
        }
    } else {
        #pragma unroll
        for (int ni = 0; ni < 8; ++ni) {
            int col = wc + ni * 16 + fr;
            if (col >= N) continue;
            #pragma unroll
            for (int mi = 0; mi < 4; ++mi) {
                int rbase = bm + wr + mi * 16 + fq * 4;
                #pragma unroll
                for (int rr = 0; rr < 4; ++rr) {
                    int row = rbase + rr;
                    if (row >= M) continue;
                    float v = acc[mi][ni][rr] + bv[ni];
                    if (relu) v = fmaxf(v, 0.f);
                    size_t o = (size_t)z * sC + (size_t)row * N + col;
                    if (Cf) Cf[o] = v;
                    if (Cb) Cb[o] = f2b(v);
                }
            }
        }
    }
}

// ---------------------------------------------------------------------------
// FUSED layer kernel: per 64-row block of class z:
//   phase G-u: gather u rows (by-col CSR) directly into LDS (bf16)
//   phase 1:   acc  = U @ Gt^T    (K=256, B staged per 32-K chunk)
//   reg:       acc  = relu(acc + gb)
//   phase G-v: gather v rows (by-row CSR) into same LDS
//   phase 2:   acc += V @ Dt^T
//   epilogue:  C = bf16(acc + deg*db), LDS repack, coalesced store
// Out must NOT alias T. LDS: Au[64][264] + Bs[8192] = 50KB -> 3 blocks/CU.
// ---------------------------------------------------------------------------
__global__ __launch_bounds__(256, 3) void gather_dual(
    const u16* __restrict__ T, size_t sAct,
    const int* __restrict__ cptrs, const u16* __restrict__ coth,
    const int* __restrict__ rptrs, const u16* __restrict__ roth,
    const float* __restrict__ dinv,
    const u16* __restrict__ Gt, const u16* __restrict__ Dt, size_t sW,
    const float* __restrict__ gbias, const float* __restrict__ dbias, int sBias,
    const float* __restrict__ degf,
    u16* __restrict__ C, int nwg)
{
    const int logical = chunk_swz(blockIdx.x, nwg);
    const int z = logical / 313, bx = logical % 313;
    const int bm = bx * 64;

    const u16* Tz = T + (size_t)z * sAct;
    const int* cptr = cptrs + (size_t)z * 20001;
    const int* rptr = rptrs + (size_t)z * 20001;
    const u16* co = coth + (size_t)z * NEDGE;
    const u16* ro = roth + (size_t)z * NEDGE;
    const float* dv = dinv + (size_t)z * NNODES;
    const u16* G = Gt + (size_t)z * sW;
    const u16* D = Dt + (size_t)z * sW;
    const float* gb = gbias + (size_t)z * sBias;
    const float* db = dbias + (size_t)z * sBias;
    const float* dgf = degf + (size_t)z * NNODES;
    u16* Cz = C + (size_t)z * sAct;

    __shared__ u16 sm[25088];      // Au: [0,16896) stride 264; Bs: [16896,25088)
    u16* Au = sm;
    u16* Bs = sm + 16896;

    const int tid  = threadIdx.x;
    const int wave = tid >> 6;
    const int lane = tid & 63;
    const int f = lane * 4;        // gather: lane covers feats [f, f+4)

    const int ar = tid >> 2, aj = (tid & 3) * 8;
    const int fr = lane & 15;
    const int fq = lane >> 4;
    const int kg = fq * 8;
    const int wr = (wave >> 1) * 32;
    const int wc = (wave & 1) * 128;

    // ---- phase G-u ----
    for (int i = 0; i < 16; ++i) {
        const int nl = wave * 16 + i;
        const int node = bm + nl;
        float ax = 0.f, ay = 0.f, az = 0.f, aw = 0.f;
        if (node < NNODES) {
            const float dn = dv[node];
            ushort4 tn = *(const ushort4*)&Tz[(size_t)node * HID + f];
            ax = dn * b2f(tn.x); ay = dn * b2f(tn.y);
            az = dn * b2f(tn.z); aw = dn * b2f(tn.w);
            const int s0 = cptr[node], s1 = cptr[node + 1];
            int e = s0;
            for (; e + 4 <= s1; e += 4) {
                int r0 = co[e], r1 = co[e + 1], r2 = co[e + 2], r3 = co[e + 3];
                float d0 = dv[r0], d1 = dv[r1], d2 = dv[r2], d3 = dv[r3];
                ushort4 u0 = *(const ushort4*)&Tz[(size_t)r0 * HID + f];
                ushort4 u1 = *(const ushort4*)&Tz[(size_t)r1 * HID + f];
                ushort4 u2 = *(const ushort4*)&Tz[(size_t)r2 * HID + f];
                ushort4 u3 = *(const ushort4*)&Tz[(size_t)r3 * HID + f];
                ax += d0 * b2f(u0.x) + d1 * b2f(u1.x) + d2 * b2f(u2.x) + d3 * b2f(u3.x);
                ay += d0 * b2f(u0.y) + d1 * b2f(u1.y) + d2 * b2f(u2.y) + d3 * b2f(u3.y);
                az += d0 * b2f(u0.z) + d1 * b2f(u1.z) + d2 * b2f(u2.z) + d3 * b2f(u3.z);
                aw += d0 * b2f(u0.w) + d1 * b2f(u1.w) + d2 * b2f(u2.w) + d3 * b2f(u3.w);
            }
            for (; e < s1; ++e) {
                int r = co[e];
                float dr = dv[r];
                ushort4 u = *(const ushort4*)&Tz[(size_t)r * HID + f];
                ax += dr * b2f(u.x); ay += dr * b2f(u.y);
                az += dr * b2f(u.z); aw += dr * b2f(u.w);
            }
            ax *= dn; ay *= dn; az *= dn; aw *= dn;
        }
        *(ushort4*)&Au[nl * 264 + f] = f2b4(ax, ay, az, aw);
    }
    __syncthreads();

    f32x4 zero = {0.f, 0.f, 0.f, 0.f};
    f32x4 acc[2][8];
    #pragma unroll
    for (int mi = 0; mi < 2; ++mi)
        #pragma unroll
        for (int ni = 0; ni < 8; ++ni) acc[mi][ni] = zero;

    // ---- phase 1: U @ Gt ----
    for (int k0 = 0; k0 < HID; k0 += 32) {
        #pragma unroll
        for (int c = 0; c < 4; ++c)
            async_copy16(G + (size_t)(c * 64 + ar) * HID + aj + k0,
                         Bs + ((size_t)c * 256 + tid) * 8);
        __syncthreads();
        short8 af[2], bfr[8];
        #pragma unroll
        for (int mi = 0; mi < 2; ++mi)
            af[mi] = *(const short8*)&Au[(wr + mi * 16 + fr) * 264 + k0 + kg];
        #pragma unroll
        for (int ni = 0; ni < 8; ++ni)
            bfr[ni] = *(const short8*)&Bs[(wc + ni * 16 + fr) * 32 + kg];
        #pragma unroll
        for (int mi = 0; mi < 2; ++mi)
            #pragma unroll
            for (int ni = 0; ni < 8; ++ni)
                acc[mi][ni] = __builtin_amdgcn_mfma_f32_16x16x32_bf16(
                    af[mi], bfr[ni], acc[mi][ni], 0, 0, 0);
        __syncthreads();
    }

    // ---- in-register: relu(acc + gb) ----
    {
        float gv[8];
        #pragma unroll
        for (int ni = 0; ni < 8; ++ni) gv[ni] = gb[wc + ni * 16 + fr];
        #pragma unroll
        for (int mi = 0; mi < 2; ++mi)
            #pragma unroll
            for (int ni = 0; ni < 8; ++ni)
                #pragma unroll
                for (int rr = 0; rr < 4; ++rr)
                    acc[mi][ni][rr] = fmaxf(acc[mi][ni][rr] + gv[ni], 0.f);
    }

    // ---- phase G-v (overwrites Au; phase-1 reads done) ----
    for (int i = 0; i < 16; ++i) {
        const int nl = wave * 16 + i;
        const int node = bm + nl;
        float bxx = 0.f, byy = 0.f, bzz = 0.f, bww = 0.f;
        if (node < NNODES) {
            ushort4 tn = *(const ushort4*)&Tz[(size_t)node * HID + f];
            const int s0 = rptr[node], s1 = rptr[node + 1];
            int e = s0;
            for (; e + 4 <= s1; e += 4) {
                int r0 = ro[e], r1 = ro[e + 1], r2 = ro[e + 2], r3 = ro[e + 3];
                ushort4 u0 = *(const ushort4*)&Tz[(size_t)r0 * HID + f];
                ushort4 u1 = *(const ushort4*)&Tz[(size_t)r1 * HID + f];
                ushort4 u2 = *(const ushort4*)&Tz[(size_t)r2 * HID + f];
                ushort4 u3 = *(const ushort4*)&Tz[(size_t)r3 * HID + f];
                bxx += b2f(u0.x) + b2f(u1.x) + b2f(u2.x) + b2f(u3.x);
                byy += b2f(u0.y) + b2f(u1.y) + b2f(u2.y) + b2f(u3.y);
                bzz += b2f(u0.z) + b2f(u1.z) + b2f(u2.z) + b2f(u3.z);
                bww += b2f(u0.w) + b2f(u1.w) + b2f(u2.w) + b2f(u3.w);
            }
            for (; e < s1; ++e) {
                int cc = ro[e];
                ushort4 u = *(const ushort4*)&Tz[(size_t)cc * HID + f];
                bxx += b2f(u.x); byy += b2f(u.y);
                bzz += b2f(u.z); bww += b2f(u.w);
            }
            bxx *= b2f(tn.x); byy *= b2f(tn.y);
            bzz *= b2f(tn.z); bww *= b2f(tn.w);
        }
        *(ushort4*)&Au[nl * 264 + f] = f2b4(bxx, byy, bzz, bww);
    }
    __syncthreads();

    // ---- phase 2: + V @ Dt ----
    for (int k0 = 0; k0 < HID; k0 += 32) {
        #pragma unroll
        for (int c = 0; c < 4; ++c)
            async_copy16(D + (size_t)(c * 64 + ar) * HID + aj + k0,
                         Bs + ((size_t)c * 256 + tid) * 8);
        __syncthreads();
        short8 af[2], bfr[8];
        #pragma unroll
        for (int mi = 0; mi < 2; ++mi)
            af[mi] = *(const short8*)&Au[(wr + mi * 16 + fr) * 264 + k0 + kg];
        #pragma unroll
        for (int ni = 0; ni < 8; ++ni)
            bfr[ni] = *(const short8*)&Bs[(wc + ni * 16 + fr) * 32 + kg];
        #pragma unroll
        for (int mi = 0; mi < 2; ++mi)
            #pragma unroll
            for (int ni = 0; ni < 8; ++ni)
                acc[mi][ni] = __builtin_amdgcn_mfma_f32_16x16x32_bf16(
                    af[mi], bfr[ni], acc[mi][ni], 0, 0, 0);
        __syncthreads();
    }

    // ---- epilogue: + deg*db, LDS repack, coalesced store ----
    float dv8[8];
    #pragma unroll
    for (int ni = 0; ni < 8; ++ni) dv8[ni] = db[wc + ni * 16 + fr];
    u16* R = sm;
    #pragma unroll
    for (int mi = 0; mi < 2; ++mi) {
        #pragma unroll
        for (int rr = 0; rr < 4; ++rr) {
            int rl = wr + mi * 16 + fq * 4 + rr;
            int grow = bm + rl;
            float dg = (grow < NNODES) ? dgf[grow] : 0.f;
            #pragma unroll
            for (int ni = 0; ni < 8; ++ni)
                R[rl * 264 + wc + ni * 16 + fr] =
                    f2b(acc[mi][ni][rr] + dg * dv8[ni]);
        }
    }
    __syncthreads();
    #pragma unroll
    for (int p = 0; p < 8; ++p) {
        int idx = p * 256 + tid;
        int lr = idx >> 5, ch = idx & 31;
        int grow = bm + lr;
        if (grow < NNODES)
            *(short8*)&Cz[(size_t)grow * 256 + ch * 8] =
                *(const short8*)&R[lr * 264 + ch * 8];
    }
}

// ---------------------------------------------------------------------------
// Fused fc1: A row b = concat(t[src[b]], t[dst[b]], t[src]*t[dst])
// ---------------------------------------------------------------------------
__global__ __launch_bounds__(256) void fc1_fused(
    const u16* __restrict__ tb, const int* __restrict__ src, const int* __restrict__ dst,
    const u16* __restrict__ Wt, const float* __restrict__ bias, u16* __restrict__ p1b)
{
    const int z = blockIdx.z;
    const u16* T = tb + (size_t)z * NNODES * HID;
    const u16* Bt = Wt + (size_t)z * 384 * 768;
    const float* bi = bias + (size_t)z * 384;
    u16* C = p1b + (size_t)z * NPAIR * 384;

    __shared__ u16 As[128 * 32];
    __shared__ u16 Bs[128 * 32];
    const int tid  = threadIdx.x;
    const int wave = tid >> 6;
    const int lane = tid & 63;
    const int bm = blockIdx.x * 128;
    const int bn = blockIdx.y * 128;
    const int wr = (wave >> 1) * 64;
    const int wc = (wave & 1) * 64;

    const int srow = wave * 32 + (lane >> 2);
    const int scol = (lane & 3) * 8;
    const int b0 = bm + srow, b1 = b0 + 16;
    const int s0i = src[b0], d0i = dst[b0];
    const int s1i = src[b1], d1i = dst[b1];

    const u16* Bg0 = Bt + (size_t)(bn + srow) * 768 + scol;
    const u16* Bg1 = Bg0 + (size_t)16 * 768;
    u16* As0 = &As[wave * 1024];
    u16* As1 = As0 + 512;
    u16* Bs0 = &Bs[wave * 1024];
    u16* Bs1 = Bs0 + 512;
    u16* Aw0 = As0 + lane * 8;
    u16* Aw1 = As1 + lane * 8;

    const int fr = lane & 15;
    const int kg = (lane >> 4) * 8;

    f32x4 zero = {0.f, 0.f, 0.f, 0.f};
    f32x4 acc[4][4];
    #pragma unroll
    for (int mi = 0; mi < 4; ++mi)
        #pragma unroll
        for (int ni = 0; ni < 4; ++ni) acc[mi][ni] = zero;

    for (int k0 = 0; k0 < 768; k0 += 32) {
        if (k0 < 512) {
            const u16* r0p = (k0 < 256) ? (T + (size_t)s0i * HID + k0 + scol)
                                        : (T + (size_t)d0i * HID + (k0 - 256) + scol);
            const u16* r1p = (k0 < 256) ? (T + (size_t)s1i * HID + k0 + scol)
                                        : (T + (size_t)d1i * HID + (k0 - 256) + scol);
            async_copy16(r0p, As0);
            async_copy16(r1p, As1);
        } else {
            int kk = k0 - 512 + scol;
            short8 a0 = *(const short8*)&T[(size_t)s0i * HID + kk];
            short8 c0 = *(const short8*)&T[(size_t)d0i * HID + kk];
            short8 a1 = *(const short8*)&T[(size_t)s1i * HID + kk];
            short8 c1 = *(const short8*)&T[(size_t)d1i * HID + kk];
            short8 p0, p1;
            #pragma unroll
            for (int j = 0; j < 8; ++j) {
                p0[j] = (short)f2b(b2f((u16)a0[j]) * b2f((u16)c0[j]));
                p1[j] = (short)f2b(b2f((u16)a1[j]) * b2f((u16)c1[j]));
            }
            *(short8*)Aw0 = p0;
            *(short8*)Aw1 = p1;
        }
        async_copy16(Bg0 + k0, Bs0);
        async_copy16(Bg1 + k0, Bs1);
        __syncthreads();
        short8 af[4], bfr[4];
        #pragma unroll
        for (int mi = 0; mi < 4; ++mi)
            af[mi] = *(const short8*)&As[(wr + mi * 16 + fr) * 32 + kg];
        #pragma unroll
        for (int ni = 0; ni < 4; ++ni)
            bfr[ni] = *(const short8*)&Bs[(wc + ni * 16 + fr) * 32 + kg];
        #pragma unroll
        for (int mi = 0; mi < 4; ++mi)
            #pragma unroll
            for (int ni = 0; ni < 4; ++ni)
                acc[mi][ni] = __builtin_amdgcn_mfma_f32_16x16x32_bf16(
                    af[mi], bfr[ni], acc[mi][ni], 0, 0, 0);
        __syncthreads();
    }

    const int fq = lane >> 4;
    #pragma unroll
    for (int ni = 0; ni < 4; ++ni) {
        int col = bn + wc + ni * 16 + fr;
        if (col >= 384) continue;
        float bz = bi[col];
        #pragma unroll
        for (int mi = 0; mi < 4; ++mi) {
            int rbase = bm + wr + mi * 16 + fq * 4;
            #pragma unroll
            for (int r = 0; r < 4; ++r) {
                int row = rbase + r;
                float v = fmaxf(acc[mi][ni][r] + bz, 0.f);
                C[(size_t)row * 384 + col] = f2b(v);
            }
        }
    }
}

// ---------------------------------------------------------------------------
// fp32 GEMM (fc3), batched over z
// ---------------------------------------------------------------------------
#define TBM 64
#define TBN 64
#define TBK 16
__global__ void gemm_bias_b(const float* __restrict__ A, size_t sA,
                            const float* __restrict__ B, size_t sB,
                            const float* __restrict__ bias, int sBias,
                            float* __restrict__ C, size_t sC,
                            int M, int N, int K, int ldc, int relu)
{
    const int z = blockIdx.z;
    A += (size_t)z * sA; B += (size_t)z * sB;
    bias += (size_t)z * sBias; C += (size_t)z * sC;

    __shared__ float As[TBK][TBM + 1];
    __shared__ float Bs[TBK][TBN + 1];
    const int bm = blockIdx.x * TBM;
    const int bn = blockIdx.y * TBN;
    const int tid = threadIdx.x;
    const int tm = (tid / 16) * 4;
    const int tn = (tid % 16) * 4;
    float acc[4][4] = {};

    for (int k0 = 0; k0 < K; k0 += TBK) {
        #pragma unroll
        for (int l = 0; l < 4; ++l) {
            int idx = tid + l * 256;
            int m = idx / TBK, k = idx % TBK;
            int gm = bm + m;
            float v = 0.f;
            if (gm < M) v = A[(size_t)gm * K + k0 + k];
            As[k][m] = v;
        }
        #pragma unroll
        for (int l = 0; l < 4; ++l) {
            int idx = tid + l * 256;
            int k = idx / TBN, n = idx % TBN;
            int gn = bn + n;
            float v = 0.f;
            if (gn < N) v = B[(size_t)(k0 + k) * N + gn];
            Bs[k][n] = v;
        }
        __syncthreads();
        #pragma unroll
        for (int k = 0; k < TBK; ++k) {
            float a[4], b[4];
            #pragma unroll
            for (int i = 0; i < 4; ++i) a[i] = As[k][tm + i];
            #pragma unroll
            for (int j = 0; j < 4; ++j) b[j] = Bs[k][tn + j];
            #pragma unroll
            for (int i = 0; i < 4; ++i)
                #pragma unroll
                for (int j = 0; j < 4; ++j)
                    acc[i][j] = fmaf(a[i], b[j], acc[i][j]);
        }
        __syncthreads();
    }
    #pragma unroll
    for (int i = 0; i < 4; ++i) {
        int gm = bm + tm + i;
        if (gm >= M) continue;
        #pragma unroll
        for (int j = 0; j < 4; ++j) {
            int gn = bn + tn + j;
            if (gn >= N) continue;
            float v = acc[i][j] + bias[gn];
            if (relu) v = fmaxf(v, 0.f);
            C[(size_t)gm * ldc + gn] = v;
        }
    }
}

// ---------------------------------------------------------------------------
// Setup kernels
// ---------------------------------------------------------------------------
__global__ void xconv(const float* __restrict__ x, u16* __restrict__ xb)
{
    int gid = blockIdx.x * blockDim.x + threadIdx.x;
    int i4 = gid * 4;
    int row = i4 >> 9;
    float4 v = make_float4(0.f, 0.f, 0.f, 0.f);
    if (row < NNODES) v = *(const float4*)&x[i4];
    *(ushort4*)&xb[i4] = f2b4(v.x, v.y, v.z, v.w);
}

__global__ void wtrans(const float* __restrict__ W, u16* __restrict__ Wt,
                       int K, int N, int NP)
{
    __shared__ float tile[32][33];
    const int m = blockIdx.z;
    const int k0 = blockIdx.x * 32, n0 = blockIdx.y * 32;
    const float* Wm = W + (size_t)m * K * N;
    u16* Wtm = Wt + (size_t)m * NP * K;
    const int c = threadIdx.x & 31, r = threadIdx.x >> 5;
    #pragma unroll
    for (int p = 0; p < 4; ++p)
        tile[r + p * 8][c] = Wm[(size_t)(k0 + r + p * 8) * N + n0 + c];
    __syncthreads();
    #pragma unroll
    for (int p = 0; p < 4; ++p)
        Wtm[(size_t)(n0 + r + p * 8) * K + k0 + c] = f2b(tile[c][r + p * 8]);
}

__device__ __forceinline__ int swz3584(int b) { return (b & 7) * 448 + (b >> 3); }

__global__ void hist(const int* __restrict__ edges, int* __restrict__ ptrs)
{
    int gid = swz3584(blockIdx.x) * 256 + threadIdx.x;
    int i = gid >> 17, e = gid & (NEDGE - 1);
    const int* eb = edges + (size_t)i * 2 * NEDGE;
    int r = eb[e], c = eb[NEDGE + e];
    atomicAdd(&ptrs[i * 20001 + c + 1], 1);
    atomicAdd(&ptrs[(7 + i) * 20001 + r + 1], 1);
}

#define SCN 512
__global__ void scan1(int* __restrict__ ptrs, int* __restrict__ aux)
{
    __shared__ int s[SCN];
    const int a = blockIdx.y;
    const int t = threadIdx.x;
    const int idx = blockIdx.x * SCN + t;
    int* arr = ptrs + a * 20001;
    int v = (idx < 20001) ? arr[idx] : 0;
    s[t] = v;
    __syncthreads();
    for (int off = 1; off < SCN; off <<= 1) {
        int x = (t >= off) ? s[t - off] : 0;
        __syncthreads();
        s[t] += x;
        __syncthreads();
    }
    if (idx < 20001) arr[idx] = s[t];
    if (t == SCN - 1) aux[a * 40 + blockIdx.x] = s[t];
}
__global__ void scan2(int* __restrict__ aux)
{
    if (threadIdx.x != 0) return;
    int a = blockIdx.x;
    int run = 0;
    for (int b = 0; b < 40; ++b) {
        int t = aux[a * 40 + b];
        aux[a * 40 + b] = run;
        run += t;
    }
}
__global__ void scan3(int* __restrict__ ptrs, const int* __restrict__ aux,
                      int* __restrict__ cur)
{
    const int a = blockIdx.y;
    const int idx = blockIdx.x * SCN + threadIdx.x;
    if (idx < 20001) {
        int v = ptrs[a * 20001 + idx] + aux[a * 40 + blockIdx.x];
        ptrs[a * 20001 + idx] = v;
        cur[a * 20001 + idx] = v;
    }
}
__global__ void csrfill(const int* __restrict__ edges, int* __restrict__ cur,
                        u16* __restrict__ othercol, u16* __restrict__ otherrow)
{
    int gid = swz3584(blockIdx.x) * 256 + threadIdx.x;
    int i = gid >> 17, e = gid & (NEDGE - 1);
    const int* eb = edges + (size_t)i * 2 * NEDGE;
    int r = eb[e], c = eb[NEDGE + e];
    int pc = atomicAdd(&cur[i * 20001 + c], 1);
    othercol[(size_t)i * NEDGE + pc] = (u16)r;
    int pr = atomicAdd(&cur[(7 + i) * 20001 + r], 1);
    otherrow[(size_t)i * NEDGE + pr] = (u16)c;
}
__global__ void mkdinv(const int* __restrict__ ptrs, float* __restrict__ dinv,
                       float* __restrict__ degf)
{
    int gid = blockIdx.x * blockDim.x + threadIdx.x;
    if (gid >= NCLS * NNODES) return;
    int i = gid / NNODES, n = gid - i * NNODES;
    int d = ptrs[i * 20001 + n + 1] - ptrs[i * 20001 + n];
    dinv[gid] = rsqrtf((float)d + 1.0f);
    int dr = ptrs[(7 + i) * 20001 + n + 1] - ptrs[(7 + i) * 20001 + n];
    degf[gid] = (float)dr;
}

// ---------------------------------------------------------------------------
// BatchNorm apply (stats accumulated by gemm_fn)
// ---------------------------------------------------------------------------
__global__ void bn_relu_b(const u16* __restrict__ xwb, const float* __restrict__ stats,
                          const float* __restrict__ gamma, const float* __restrict__ beta,
                          u16* __restrict__ tb)
{
    const int z = blockIdx.y;
    const int gid = blockIdx.x * blockDim.x + threadIdx.x;
    const int n = gid >> 6, f4 = (gid & 63) * 4;
    const u16* X = xwb + (size_t)z * NNODES * HID;
    u16* T = tb + (size_t)z * NNODES * HID;
    const float* st = stats + z * 2 * HID;
    const float invN = 1.0f / NNODES;
    float4 su = *(const float4*)&st[f4];
    float4 sq = *(const float4*)&st[HID + f4];
    float4 g  = *(const float4*)&gamma[(size_t)z * HID + f4];
    float4 be = *(const float4*)&beta[(size_t)z * HID + f4];
    ushort4 u = *(const ushort4*)&X[(size_t)n * HID + f4];
    float4 x = b2f4(u);
    float o[4], mu, var;
    mu = su.x * invN; var = sq.x * invN - mu * mu;
    o[0] = fmaxf((x.x - mu) * rsqrtf(var + BN_EPS) * g.x + be.x, 0.f);
    mu = su.y * invN; var = sq.y * invN - mu * mu;
    o[1] = fmaxf((x.y - mu) * rsqrtf(var + BN_EPS) * g.y + be.y, 0.f);
    mu = su.z * invN; var = sq.z * invN - mu * mu;
    o[2] = fmaxf((x.z - mu) * rsqrtf(var + BN_EPS) * g.z + be.z, 0.f);
    mu = su.w * invN; var = sq.w * invN - mu * mu;
    o[3] = fmaxf((x.w - mu) * rsqrtf(var + BN_EPS) * g.w + be.w, 0.f);
    *(ushort4*)&T[(size_t)n * HID + f4] = f2b4(o[0], o[1], o[2], o[3]);
}

__global__ void final_cls(const float* __restrict__ outs, const float* __restrict__ clsW,
                          const float* __restrict__ clsb, float* __restrict__ out)
{
    const int gid = blockIdx.x * blockDim.x + threadIdx.x;
    if (gid >= NPAIR * NCLS) return;
    const int b = gid / NCLS, c = gid % NCLS;
    float acc = clsb[c];
    const float* row = outs + (size_t)b * 112;
    #pragma unroll 4
    for (int k = 0; k < 112; ++k)
        acc = fmaf(fmaxf(row[k], 0.f), clsW[k * NCLS + c], acc);
    out[gid] = acc;
}

// ---------------------------------------------------------------------------
extern "C" void kernel_launch(void* const* d_in, const int* in_sizes, int n_in,
                              void* d_out, int out_size, void* d_ws, size_t ws_size,
                              hipStream_t stream)
{
    const float* x        = (const float*)d_in[0];
    const int*   edges    = (const int*)  d_in[1];
    const int*   node_id  = (const int*)  d_in[2];
    const float* lin0_W   = (const float*)d_in[3];
    const float* lin0_b   = (const float*)d_in[4];
    const float* bn_gamma = (const float*)d_in[5];
    const float* bn_beta  = (const float*)d_in[6];
    const float* gcn_W    = (const float*)d_in[7];
    const float* gcn_b    = (const float*)d_in[8];
    const float* dp_W     = (const float*)d_in[9];
    const float* dp_b     = (const float*)d_in[10];
    const float* fc1_W    = (const float*)d_in[11];
    const float* fc1_b    = (const float*)d_in[12];
    const float* fc2_W    = (const float*)d_in[13];
    const float* fc2_b    = (const float*)d_in[14];
    const float* fc3_W    = (const float*)d_in[15];
    const float* fc3_b    = (const float*)d_in[16];
    const float* cls_W    = (const float*)d_in[17];
    const float* cls_b    = (const float*)d_in[18];
    float* out = (float*)d_out;

    unsigned char* w = (unsigned char*)d_ws;
    size_t used = 0;
    auto alloc = [&](size_t bytes) {
        void* p = (void*)(w + used);
        used += (bytes + 255) & ~(size_t)255;
        return p;
    };
    u16*   xb       = (u16*)  alloc((size_t)MPAD * DIN * 2);
    u16*   lin0Wt   = (u16*)  alloc((size_t)NCLS * HID * DIN * 2);
    u16*   gcnWt    = (u16*)  alloc((size_t)NCLS * NLAY * HID * HID * 2);
    u16*   dpWt     = (u16*)  alloc((size_t)NCLS * NLAY * HID * HID * 2);
    u16*   fc1Wt    = (u16*)  alloc((size_t)NCLS * 384 * 768 * 2);
    u16*   fc2Wt    = (u16*)  alloc((size_t)NCLS * 256 * 384 * 2);
    int*   ptrs     = (int*)  alloc((size_t)14 * 20001 * 4);
    int*   cur      = (int*)  alloc((size_t)14 * 20001 * 4);
    int*   aux      = (int*)  alloc((size_t)14 * 40 * 4);
    u16*   othercol = (u16*)  alloc((size_t)NCLS * NEDGE * 2);
    u16*   otherrow = (u16*)  alloc((size_t)NCLS * NEDGE * 2);
    float* dinv     = (float*)alloc((size_t)NCLS * NNODES * 4);
    float* degf     = (float*)alloc((size_t)NCLS * NNODES * 4);
    float* outsb    = (float*)alloc((size_t)NPAIR * 112 * 4);
    float* stats    = (float*)alloc((size_t)NCLS * 2 * HID * 4);

    // class-group size g: 3 big activation buffers
    int g = 1;
    for (int t = NCLS; t >= 1; --t) {
        size_t big = ((size_t)t * NNODES + 96) * HID * 2;
        big = (big + 255) & ~(size_t)255;
        if (used + 3 * big <= ws_size) { g = t; break; }
    }
    size_t bigBytes = ((size_t)g * NNODES + 96) * HID * 2;
    u16* tbA  = (u16*)alloc(bigBytes);
    u16* ubuf = (u16*)alloc(bigBytes);
    u16* vbuf = (u16*)alloc(bigBytes);
    u16*   p1b = vbuf;           // head stage reuse
    float* p2f = (float*)ubuf;   // head stage reuse (t ends in tbA)

    const int* src = node_id;
    const int* dst = node_id + NPAIR;

    // ---- setup ----
    xconv<<<(MPAD * DIN / 4) / 256, 256, 0, stream>>>(x, xb);
    wtrans<<<dim3(16, 8, 7),  256, 0, stream>>>(lin0_W, lin0Wt, 512, 256, 256);
    wtrans<<<dim3(8, 8, 14),  256, 0, stream>>>(gcn_W,  gcnWt,  256, 256, 256);
    wtrans<<<dim3(8, 8, 14),  256, 0, stream>>>(dp_W,   dpWt,   256, 256, 256);
    wtrans<<<dim3(24, 12, 7), 256, 0, stream>>>(fc1_W,  fc1Wt,  768, 384, 384);
    wtrans<<<dim3(12, 6, 7),  256, 0, stream>>>(fc2_W,  fc2Wt,  384, 192, 256);

    hipMemsetAsync(ptrs, 0, (size_t)14 * 20001 * 4, stream);
    hist<<<(NCLS * NEDGE) / 256, 256, 0, stream>>>(edges, ptrs);
    scan1<<<dim3(40, 14), SCN, 0, stream>>>(ptrs, aux);
    scan2<<<14, 64, 0, stream>>>(aux);
    scan3<<<dim3(40, 14), SCN, 0, stream>>>(ptrs, aux, cur);
    csrfill<<<(NCLS * NEDGE) / 256, 256, 0, stream>>>(edges, cur, othercol, otherrow);
    mkdinv<<<(NCLS * NNODES + 255) / 256, 256, 0, stream>>>(ptrs, dinv, degf);

    const size_t sT = (size_t)NNODES * HID;

    for (int cb = 0; cb < NCLS; cb += g) {
        const int gl = min(g, NCLS - cb);
        const int nwg = gl * 313;    // fused layer kernel: 64-row blocks

        // lin0 (A shared, fused colstats) -> ubuf ; BN+ReLU -> tbA
        hipMemsetAsync(stats, 0, (size_t)gl * 2 * HID * 4, stream);
        gemm_fn<<<dim3(157, 1, gl), 256, 0, stream>>>(
            xb, 0, lin0Wt + (size_t)cb * HID * DIN, (size_t)HID * DIN,
            lin0_b + cb * HID, HID, nullptr, ubuf, sT, NNODES, HID, DIN, 0, stats);
        bn_relu_b<<<dim3(5000, gl), 256, 0, stream>>>(
            ubuf, stats, bn_gamma + cb * HID, bn_beta + cb * HID, tbA);

        u16* t_cur = tbA;
        u16* t_alt = ubuf;
        for (int j = 0; j < NLAY; ++j) {
            gather_dual<<<nwg, 256, 0, stream>>>(
                t_cur, sT,
                ptrs + cb * 20001, othercol + (size_t)cb * NEDGE,
                ptrs + (7 + cb) * 20001, otherrow + (size_t)cb * NEDGE,
                dinv + (size_t)cb * NNODES,
                gcnWt + ((size_t)cb * NLAY + j) * HID * HID,
                dpWt  + ((size_t)cb * NLAY + j) * HID * HID,
                (size_t)NLAY * HID * HID,
                gcn_b + ((size_t)cb * NLAY + j) * HID,
                dp_b  + ((size_t)cb * NLAY + j) * HID, NLAY * HID,
                degf + (size_t)cb * NNODES,
                t_alt, nwg);
            u16* tmp = t_cur; t_cur = t_alt; t_alt = tmp;
        }
        // after even NLAY, t_cur == tbA ; ubuf/vbuf free

        fc1_fused<<<dim3(64, 3, gl), 256, 0, stream>>>(
            t_cur, src, dst, fc1Wt + (size_t)cb * 384 * 768, fc1_b + cb * 384, p1b);
        gemm_fn<<<dim3(64, 1, gl), 256, 0, stream>>>(
            p1b, (size_t)NPAIR * 384, fc2Wt + (size_t)cb * 256 * 384, (size_t)256 * 384,
            fc2_b + cb * 192, 192, p2f, nullptr, (size_t)NPAIR * 192,
            NPAIR, 192, 384, 1, nullptr);
        gemm_bias_b<<<dim3(128, 1, gl), 256, 0, stream>>>(
            p2f, (size_t)NPAIR * 192, fc3_W + (size_t)cb * 192 * 16, (size_t)192 * 16,
            fc3_b + cb * 16, 16, outsb + cb * 16, 16,
            NPAIR, 16, 192, 112, 0);
    }

    final_cls<<<(NPAIR * NCLS + 255) / 256, 256, 0, stream>>>(outsb, cls_W, cls_b, out);
}

// Round 15
// 864.594 us; speedup vs baseline: 1.1954x; 1.1954x over previous
//
#include <hip/hip_runtime.h>

typedef unsigned short u16;
typedef unsigned int   u32;
typedef __attribute__((ext_vector_type(8))) short short8;
typedef __attribute__((ext_vector_type(4))) float f32x4;

#define NNODES 20000
#define MPAD   20096          // 157*128
#define DIN    512
#define HID    256
#define NCLS   7
#define NLAY   2
#define NEDGE  131072
#define NPAIR  8192
#define BN_EPS 1e-5f

__device__ __forceinline__ void atomAddF(float* p, float v) { unsafeAtomicAdd(p, v); }

__device__ __forceinline__ float b2f(u16 u) {
    u32 x = ((u32)u) << 16;
    return __builtin_bit_cast(float, x);
}
__device__ __forceinline__ u16 f2b(float f) {
    u32 u = __builtin_bit_cast(u32, f);
    u32 r = u + 0x7FFFu + ((u >> 16) & 1u);
    return (u16)(r >> 16);
}
__device__ __forceinline__ float4 b2f4(ushort4 u) {
    return make_float4(b2f(u.x), b2f(u.y), b2f(u.z), b2f(u.w));
}
__device__ __forceinline__ ushort4 f2b4(float a, float b, float c, float d) {
    ushort4 o; o.x = f2b(a); o.y = f2b(b); o.z = f2b(c); o.w = f2b(d); return o;
}

__device__ __forceinline__ void async_copy16(const u16* g, u16* l) {
    __builtin_amdgcn_global_load_lds((const __attribute__((address_space(1))) void*)g,
                                     (__attribute__((address_space(3))) void*)l, 16, 0, 0);
}

// bijective chunk swizzle (m204 form): each XCD owns a contiguous logical range
__device__ __forceinline__ int chunk_swz(int orig, int nwg) {
    int xcd = orig & 7, q = nwg >> 3, r = nwg & 7;
    int base = (xcd < r) ? xcd * (q + 1) : r * (q + 1) + (xcd - r) * q;
    return base + (orig >> 3);
}

// ---------------------------------------------------------------------------
// Full-N bf16 MFMA GEMM (N<=256): per z: C = A[z] @ Bt[z]^T (+bias)(opt relu)
// statsOut != nullptr: additionally accumulate per-column sum/sumsq of
// (acc+bias) (pre-relu) into statsOut[z*512 + {0,256} + col]  (for BatchNorm).
// ---------------------------------------------------------------------------
__global__ __launch_bounds__(256, 2) void gemm_fn(
    const u16* __restrict__ A, size_t sA, const u16* __restrict__ Bt, size_t sB,
    const float* __restrict__ bias, int sBias,
    float* __restrict__ Cf, u16* __restrict__ Cb, size_t sC,
    int M, int N, int K, int relu, float* statsOut)
{
    const int z = blockIdx.z;
    A  += (size_t)z * sA;
    Bt += (size_t)z * sB;
    if (bias) bias += (size_t)z * sBias;

    __shared__ u16 sm[12288];
    __shared__ float sred[512];
    u16* As = sm;
    u16* Bs = sm + 4096;

    const int tid  = threadIdx.x;
    const int wave = tid >> 6;
    const int lane = tid & 63;
    const int bm = blockIdx.x * 128;
    const int wr = (wave >> 1) * 64;
    const int wc = (wave & 1) * 128;

    const int ar = tid >> 2, aj = (tid & 3) * 8;
    const u16* AgA = A + (size_t)(bm + ar) * K + aj;
    const u16* AgB = A + (size_t)(bm + ar + 64) * K + aj;
    u16* AsA = As + tid * 8;
    u16* AsB = As + tid * 8 + 2048;
    const u16* BgC[4]; u16* BsC[4];
    #pragma unroll
    for (int c = 0; c < 4; ++c) {
        BgC[c] = Bt + (size_t)(c * 64 + ar) * K + aj;
        BsC[c] = Bs + ((size_t)c * 256 + tid) * 8;
    }

    const int fr = lane & 15;
    const int fq = lane >> 4;
    const int kg = fq * 8;

    f32x4 zero = {0.f, 0.f, 0.f, 0.f};
    f32x4 acc[4][8];
    #pragma unroll
    for (int mi = 0; mi < 4; ++mi)
        #pragma unroll
        for (int ni = 0; ni < 8; ++ni) acc[mi][ni] = zero;

    for (int k0 = 0; k0 < K; k0 += 32) {
        async_copy16(AgA + k0, AsA);
        async_copy16(AgB + k0, AsB);
        #pragma unroll
        for (int c = 0; c < 4; ++c) async_copy16(BgC[c] + k0, BsC[c]);
        __syncthreads();
        short8 af[4], bfr[8];
        #pragma unroll
        for (int mi = 0; mi < 4; ++mi)
            af[mi] = *(const short8*)&As[(wr + mi * 16 + fr) * 32 + kg];
        #pragma unroll
        for (int ni = 0; ni < 8; ++ni)
            bfr[ni] = *(const short8*)&Bs[(wc + ni * 16 + fr) * 32 + kg];
        #pragma unroll
        for (int mi = 0; mi < 4; ++mi)
            #pragma unroll
            for (int ni = 0; ni < 8; ++ni)
                acc[mi][ni] = __builtin_amdgcn_mfma_f32_16x16x32_bf16(
                    af[mi], bfr[ni], acc[mi][ni], 0, 0, 0);
        __syncthreads();
    }

    float bv[8];
    #pragma unroll
    for (int ni = 0; ni < 8; ++ni) {
        int col = wc + ni * 16 + fr;
        bv[ni] = (bias && col < N) ? bias[col] : 0.f;
    }

    // fused column statistics (BatchNorm): block-level LDS reduce -> atomics
    if (statsOut) {
        sred[tid] = 0.f; sred[256 + tid] = 0.f;
        __syncthreads();
        #pragma unroll
        for (int ni = 0; ni < 8; ++ni) {
            int col = wc + ni * 16 + fr;
            float s = 0.f, sq = 0.f;
            #pragma unroll
            for (int mi = 0; mi < 4; ++mi)
                #pragma unroll
                for (int rr = 0; rr < 4; ++rr) {
                    int row = bm + wr + mi * 16 + fq * 4 + rr;
                    if (row < M) {
                        float v = acc[mi][ni][rr] + bv[ni];
                        s += v; sq += v * v;
                    }
                }
            atomicAdd(&sred[col], s);
            atomicAdd(&sred[256 + col], sq);
        }
        __syncthreads();
        atomAddF(&statsOut[(size_t)z * 512 + tid], sred[tid]);
        atomAddF(&statsOut[(size_t)z * 512 + 256 + tid], sred[256 + tid]);
    }

    if (Cb && N == 256) {
        u16* R = sm;
        const int lrb = (wave >> 1) * 16 + fq * 4;
        const int cb0 = wc + fr;
        #pragma unroll
        for (int mi = 0; mi < 4; ++mi) {
            __syncthreads();
            #pragma unroll
            for (int ni = 0; ni < 8; ++ni)
                #pragma unroll
                for (int rr = 0; rr < 4; ++rr) {
                    float v = acc[mi][ni][rr] + bv[ni];
                    if (relu) v = fmaxf(v, 0.f);
                    R[(lrb + rr) * 264 + cb0 + ni * 16] = f2b(v);
                }
            __syncthreads();
            #pragma unroll
            for (int p = 0; p < 4; ++p) {
                int idx = p * 256 + tid;
                int lr = idx >> 5, ch = idx & 31;
                int grow = bm + (lr >> 4) * 64 + mi * 16 + (lr & 15);
                if (grow < M)
                    *(short8*)&Cb[(size_t)z * sC + (size_t)grow * 256 + ch * 8] =
                        *(const short8*)&R[lr * 264 + ch * 8];
            }
        }
    } else {
        #pragma unroll
        for (int ni = 0; ni < 8; ++ni) {
            int col = wc + ni * 16 + fr;
            if (col >= N) continue;
            #pragma unroll
            for (int mi = 0; mi < 4; ++mi) {
                int rbase = bm + wr + mi * 16 + fq * 4;
                #pragma unroll
                for (int rr = 0; rr < 4; ++rr) {
                    int row = rbase + rr;
                    if (row >= M) continue;
                    float v = acc[mi][ni][rr] + bv[ni];
                    if (relu) v = fmaxf(v, 0.f);
                    size_t o = (size_t)z * sC + (size_t)row * N + col;
                    if (Cf) Cf[o] = v;
                    if (Cb) Cb[o] = f2b(v);
                }
            }
        }
    }
}

// ---------------------------------------------------------------------------
// Dual GEMM (layer update): C = relu(U@Gt^T + gb) + V@Dt^T + deg*db  (bf16)
// NOTE: C may ALIAS U — each block only reads its own 128 A-rows, and all
// reads complete before the epilogue stores. No __restrict__ on U/C.
// ---------------------------------------------------------------------------
__global__ __launch_bounds__(256, 2) void gemm_dual(
    const u16* U, const u16* __restrict__ V, size_t sAct,
    const u16* __restrict__ Gt, const u16* __restrict__ Dt, size_t sW,
    const float* __restrict__ gbias, const float* __restrict__ dbias, int sBias,
    const float* __restrict__ degf, size_t sDeg,
    u16* Cb, int M)
{
    const int z = blockIdx.z;
    U += (size_t)z * sAct; V += (size_t)z * sAct;
    Gt += (size_t)z * sW;  Dt += (size_t)z * sW;
    gbias += (size_t)z * sBias; dbias += (size_t)z * sBias;
    degf  += (size_t)z * sDeg;
    u16* C = Cb + (size_t)z * sAct;

    __shared__ u16 sm[12288];
    u16* As = sm;
    u16* Bs = sm + 4096;

    const int tid  = threadIdx.x;
    const int wave = tid >> 6;
    const int lane = tid & 63;
    const int bm = blockIdx.x * 128;
    const int wr = (wave >> 1) * 64;
    const int wc = (wave & 1) * 128;

    const int ar = tid >> 2, aj = (tid & 3) * 8;
    u16* AsA = As + tid * 8;
    u16* AsB = As + tid * 8 + 2048;

    const int fr = lane & 15;
    const int fq = lane >> 4;
    const int kg = fq * 8;

    f32x4 zero = {0.f, 0.f, 0.f, 0.f};
    f32x4 acc[4][8];
    #pragma unroll
    for (int mi = 0; mi < 4; ++mi)
        #pragma unroll
        for (int ni = 0; ni < 8; ++ni) acc[mi][ni] = zero;

    // ---- phase 1: U @ Gt ----
    for (int k0 = 0; k0 < HID; k0 += 32) {
        async_copy16(U + (size_t)(bm + ar) * HID + aj + k0, AsA);
        async_copy16(U + (size_t)(bm + ar + 64) * HID + aj + k0, AsB);
        #pragma unroll
        for (int c = 0; c < 4; ++c)
            async_copy16(Gt + (size_t)(c * 64 + ar) * HID + aj + k0,
                         Bs + ((size_t)c * 256 + tid) * 8);
        __syncthreads();
        short8 af[4], bfr[8];
        #pragma unroll
        for (int mi = 0; mi < 4; ++mi)
            af[mi] = *(const short8*)&As[(wr + mi * 16 + fr) * 32 + kg];
        #pragma unroll
        for (int ni = 0; ni < 8; ++ni)
            bfr[ni] = *(const short8*)&Bs[(wc + ni * 16 + fr) * 32 + kg];
        #pragma unroll
        for (int mi = 0; mi < 4; ++mi)
            #pragma unroll
            for (int ni = 0; ni < 8; ++ni)
                acc[mi][ni] = __builtin_amdgcn_mfma_f32_16x16x32_bf16(
                    af[mi], bfr[ni], acc[mi][ni], 0, 0, 0);
        __syncthreads();
    }

    // ---- in-register: relu(acc + gb) ----
    {
        float gv[8];
        #pragma unroll
        for (int ni = 0; ni < 8; ++ni) gv[ni] = gbias[wc + ni * 16 + fr];
        #pragma unroll
        for (int mi = 0; mi < 4; ++mi)
            #pragma unroll
            for (int ni = 0; ni < 8; ++ni)
                #pragma unroll
                for (int rr = 0; rr < 4; ++rr)
                    acc[mi][ni][rr] = fmaxf(acc[mi][ni][rr] + gv[ni], 0.f);
    }

    // ---- phase 2: + V @ Dt ----
    for (int k0 = 0; k0 < HID; k0 += 32) {
        async_copy16(V + (size_t)(bm + ar) * HID + aj + k0, AsA);
        async_copy16(V + (size_t)(bm + ar + 64) * HID + aj + k0, AsB);
        #pragma unroll
        for (int c = 0; c < 4; ++c)
            async_copy16(Dt + (size_t)(c * 64 + ar) * HID + aj + k0,
                         Bs + ((size_t)c * 256 + tid) * 8);
        __syncthreads();
        short8 af[4], bfr[8];
        #pragma unroll
        for (int mi = 0; mi < 4; ++mi)
            af[mi] = *(const short8*)&As[(wr + mi * 16 + fr) * 32 + kg];
        #pragma unroll
        for (int ni = 0; ni < 8; ++ni)
            bfr[ni] = *(const short8*)&Bs[(wc + ni * 16 + fr) * 32 + kg];
        #pragma unroll
        for (int mi = 0; mi < 4; ++mi)
            #pragma unroll
            for (int ni = 0; ni < 8; ++ni)
                acc[mi][ni] = __builtin_amdgcn_mfma_f32_16x16x32_bf16(
                    af[mi], bfr[ni], acc[mi][ni], 0, 0, 0);
        __syncthreads();
    }

    // ---- epilogue: + deg*db, repack via LDS, coalesced store ----
    float dv8[8];
    #pragma unroll
    for (int ni = 0; ni < 8; ++ni) dv8[ni] = dbias[wc + ni * 16 + fr];
    u16* R = sm;
    const int lrb = (wave >> 1) * 16 + fq * 4;
    const int cb0 = wc + fr;
    #pragma unroll
    for (int mi = 0; mi < 4; ++mi) {
        __syncthreads();
        float dgr[4];
        #pragma unroll
        for (int rr = 0; rr < 4; ++rr) {
            int grow = bm + wr + mi * 16 + fq * 4 + rr;
            dgr[rr] = (grow < M) ? degf[grow] : 0.f;
        }
        #pragma unroll
        for (int ni = 0; ni < 8; ++ni)
            #pragma unroll
            for (int rr = 0; rr < 4; ++rr)
                R[(lrb + rr) * 264 + cb0 + ni * 16] =
                    f2b(acc[mi][ni][rr] + dgr[rr] * dv8[ni]);
        __syncthreads();
        #pragma unroll
        for (int p = 0; p < 4; ++p) {
            int idx = p * 256 + tid;
            int lr = idx >> 5, ch = idx & 31;
            int grow = bm + (lr >> 4) * 64 + mi * 16 + (lr & 15);
            if (grow < M)
                *(short8*)&C[(size_t)grow * 256 + ch * 8] =
                    *(const short8*)&R[lr * 264 + ch * 8];
        }
    }
}

// ---------------------------------------------------------------------------
// Fused fc1: A row b = concat(t[src[b]], t[dst[b]], t[src]*t[dst])
// ---------------------------------------------------------------------------
__global__ __launch_bounds__(256) void fc1_fused(
    const u16* __restrict__ tb, const int* __restrict__ src, const int* __restrict__ dst,
    const u16* __restrict__ Wt, const float* __restrict__ bias, u16* __restrict__ p1b)
{
    const int z = blockIdx.z;
    const u16* T = tb + (size_t)z * NNODES * HID;
    const u16* Bt = Wt + (size_t)z * 384 * 768;
    const float* bi = bias + (size_t)z * 384;
    u16* C = p1b + (size_t)z * NPAIR * 384;

    __shared__ u16 As[128 * 32];
    __shared__ u16 Bs[128 * 32];
    const int tid  = threadIdx.x;
    const int wave = tid >> 6;
    const int lane = tid & 63;
    const int bm = blockIdx.x * 128;
    const int bn = blockIdx.y * 128;
    const int wr = (wave >> 1) * 64;
    const int wc = (wave & 1) * 64;

    const int srow = wave * 32 + (lane >> 2);
    const int scol = (lane & 3) * 8;
    const int b0 = bm + srow, b1 = b0 + 16;
    const int s0i = src[b0], d0i = dst[b0];
    const int s1i = src[b1], d1i = dst[b1];

    const u16* Bg0 = Bt + (size_t)(bn + srow) * 768 + scol;
    const u16* Bg1 = Bg0 + (size_t)16 * 768;
    u16* As0 = &As[wave * 1024];
    u16* As1 = As0 + 512;
    u16* Bs0 = &Bs[wave * 1024];
    u16* Bs1 = Bs0 + 512;
    u16* Aw0 = As0 + lane * 8;
    u16* Aw1 = As1 + lane * 8;

    const int fr = lane & 15;
    const int kg = (lane >> 4) * 8;

    f32x4 zero = {0.f, 0.f, 0.f, 0.f};
    f32x4 acc[4][4];
    #pragma unroll
    for (int mi = 0; mi < 4; ++mi)
        #pragma unroll
        for (int ni = 0; ni < 4; ++ni) acc[mi][ni] = zero;

    for (int k0 = 0; k0 < 768; k0 += 32) {
        if (k0 < 512) {
            const u16* r0p = (k0 < 256) ? (T + (size_t)s0i * HID + k0 + scol)
                                        : (T + (size_t)d0i * HID + (k0 - 256) + scol);
            const u16* r1p = (k0 < 256) ? (T + (size_t)s1i * HID + k0 + scol)
                                        : (T + (size_t)d1i * HID + (k0 - 256) + scol);
            async_copy16(r0p, As0);
            async_copy16(r1p, As1);
        } else {
            int kk = k0 - 512 + scol;
            short8 a0 = *(const short8*)&T[(size_t)s0i * HID + kk];
            short8 c0 = *(const short8*)&T[(size_t)d0i * HID + kk];
            short8 a1 = *(const short8*)&T[(size_t)s1i * HID + kk];
            short8 c1 = *(const short8*)&T[(size_t)d1i * HID + kk];
            short8 p0, p1;
            #pragma unroll
            for (int j = 0; j < 8; ++j) {
                p0[j] = (short)f2b(b2f((u16)a0[j]) * b2f((u16)c0[j]));
                p1[j] = (short)f2b(b2f((u16)a1[j]) * b2f((u16)c1[j]));
            }
            *(short8*)Aw0 = p0;
            *(short8*)Aw1 = p1;
        }
        async_copy16(Bg0 + k0, Bs0);
        async_copy16(Bg1 + k0, Bs1);
        __syncthreads();
        short8 af[4], bfr[4];
        #pragma unroll
        for (int mi = 0; mi < 4; ++mi)
            af[mi] = *(const short8*)&As[(wr + mi * 16 + fr) * 32 + kg];
        #pragma unroll
        for (int ni = 0; ni < 4; ++ni)
            bfr[ni] = *(const short8*)&Bs[(wc + ni * 16 + fr) * 32 + kg];
        #pragma unroll
        for (int mi = 0; mi < 4; ++mi)
            #pragma unroll
            for (int ni = 0; ni < 4; ++ni)
                acc[mi][ni] = __builtin_amdgcn_mfma_f32_16x16x32_bf16(
                    af[mi], bfr[ni], acc[mi][ni], 0, 0, 0);
        __syncthreads();
    }

    const int fq = lane >> 4;
    #pragma unroll
    for (int ni = 0; ni < 4; ++ni) {
        int col = bn + wc + ni * 16 + fr;
        if (col >= 384) continue;
        float bz = bi[col];
        #pragma unroll
        for (int mi = 0; mi < 4; ++mi) {
            int rbase = bm + wr + mi * 16 + fq * 4;
            #pragma unroll
            for (int r = 0; r < 4; ++r) {
                int row = rbase + r;
                float v = fmaxf(acc[mi][ni][r] + bz, 0.f);
                C[(size_t)row * 384 + col] = f2b(v);
            }
        }
    }
}

// ---------------------------------------------------------------------------
// fp32 GEMM (fc3), batched over z
// ---------------------------------------------------------------------------
#define TBM 64
#define TBN 64
#define TBK 16
__global__ void gemm_bias_b(const float* __restrict__ A, size_t sA,
                            const float* __restrict__ B, size_t sB,
                            const float* __restrict__ bias, int sBias,
                            float* __restrict__ C, size_t sC,
                            int M, int N, int K, int ldc, int relu)
{
    const int z = blockIdx.z;
    A += (size_t)z * sA; B += (size_t)z * sB;
    bias += (size_t)z * sBias; C += (size_t)z * sC;

    __shared__ float As[TBK][TBM + 1];
    __shared__ float Bs[TBK][TBN + 1];
    const int bm = blockIdx.x * TBM;
    const int bn = blockIdx.y * TBN;
    const int tid = threadIdx.x;
    const int tm = (tid / 16) * 4;
    const int tn = (tid % 16) * 4;
    float acc[4][4] = {};

    for (int k0 = 0; k0 < K; k0 += TBK) {
        #pragma unroll
        for (int l = 0; l < 4; ++l) {
            int idx = tid + l * 256;
            int m = idx / TBK, k = idx % TBK;
            int gm = bm + m;
            float v = 0.f;
            if (gm < M) v = A[(size_t)gm * K + k0 + k];
            As[k][m] = v;
        }
        #pragma unroll
        for (int l = 0; l < 4; ++l) {
            int idx = tid + l * 256;
            int k = idx / TBN, n = idx % TBN;
            int gn = bn + n;
            float v = 0.f;
            if (gn < N) v = B[(size_t)(k0 + k) * N + gn];
            Bs[k][n] = v;
        }
        __syncthreads();
        #pragma unroll
        for (int k = 0; k < TBK; ++k) {
            float a[4], b[4];
            #pragma unroll
            for (int i = 0; i < 4; ++i) a[i] = As[k][tm + i];
            #pragma unroll
            for (int j = 0; j < 4; ++j) b[j] = Bs[k][tn + j];
            #pragma unroll
            for (int i = 0; i < 4; ++i)
                #pragma unroll
                for (int j = 0; j < 4; ++j)
                    acc[i][j] = fmaf(a[i], b[j], acc[i][j]);
        }
        __syncthreads();
    }
    #pragma unroll
    for (int i = 0; i < 4; ++i) {
        int gm = bm + tm + i;
        if (gm >= M) continue;
        #pragma unroll
        for (int j = 0; j < 4; ++j) {
            int gn = bn + tn + j;
            if (gn >= N) continue;
            float v = acc[i][j] + bias[gn];
            if (relu) v = fmaxf(v, 0.f);
            C[(size_t)gm * ldc + gn] = v;
        }
    }
}

// ---------------------------------------------------------------------------
// Setup kernels
// ---------------------------------------------------------------------------
__global__ void xconv(const float* __restrict__ x, u16* __restrict__ xb)
{
    int gid = blockIdx.x * blockDim.x + threadIdx.x;
    int i4 = gid * 4;
    int row = i4 >> 9;
    float4 v = make_float4(0.f, 0.f, 0.f, 0.f);
    if (row < NNODES) v = *(const float4*)&x[i4];
    *(ushort4*)&xb[i4] = f2b4(v.x, v.y, v.z, v.w);
}

__global__ void wtrans(const float* __restrict__ W, u16* __restrict__ Wt,
                       int K, int N, int NP)
{
    __shared__ float tile[32][33];
    const int m = blockIdx.z;
    const int k0 = blockIdx.x * 32, n0 = blockIdx.y * 32;
    const float* Wm = W + (size_t)m * K * N;
    u16* Wtm = Wt + (size_t)m * NP * K;
    const int c = threadIdx.x & 31, r = threadIdx.x >> 5;
    #pragma unroll
    for (int p = 0; p < 4; ++p)
        tile[r + p * 8][c] = Wm[(size_t)(k0 + r + p * 8) * N + n0 + c];
    __syncthreads();
    #pragma unroll
    for (int p = 0; p < 4; ++p)
        Wtm[(size_t)(n0 + r + p * 8) * K + k0 + c] = f2b(tile[c][r + p * 8]);
}

__device__ __forceinline__ int swz3584(int b) { return (b & 7) * 448 + (b >> 3); }

__global__ void hist(const int* __restrict__ edges, int* __restrict__ ptrs)
{
    int gid = swz3584(blockIdx.x) * 256 + threadIdx.x;
    int i = gid >> 17, e = gid & (NEDGE - 1);
    const int* eb = edges + (size_t)i * 2 * NEDGE;
    int r = eb[e], c = eb[NEDGE + e];
    atomicAdd(&ptrs[i * 20001 + c + 1], 1);
    atomicAdd(&ptrs[(7 + i) * 20001 + r + 1], 1);
}

#define SCN 512
__global__ void scan1(int* __restrict__ ptrs, int* __restrict__ aux)
{
    __shared__ int s[SCN];
    const int a = blockIdx.y;
    const int t = threadIdx.x;
    const int idx = blockIdx.x * SCN + t;
    int* arr = ptrs + a * 20001;
    int v = (idx < 20001) ? arr[idx] : 0;
    s[t] = v;
    __syncthreads();
    for (int off = 1; off < SCN; off <<= 1) {
        int x = (t >= off) ? s[t - off] : 0;
        __syncthreads();
        s[t] += x;
        __syncthreads();
    }
    if (idx < 20001) arr[idx] = s[t];
    if (t == SCN - 1) aux[a * 40 + blockIdx.x] = s[t];
}
__global__ void scan2(int* __restrict__ aux)
{
    if (threadIdx.x != 0) return;
    int a = blockIdx.x;
    int run = 0;
    for (int b = 0; b < 40; ++b) {
        int t = aux[a * 40 + b];
        aux[a * 40 + b] = run;
        run += t;
    }
}
__global__ void scan3(int* __restrict__ ptrs, const int* __restrict__ aux,
                      int* __restrict__ cur)
{
    const int a = blockIdx.y;
    const int idx = blockIdx.x * SCN + threadIdx.x;
    if (idx < 20001) {
        int v = ptrs[a * 20001 + idx] + aux[a * 40 + blockIdx.x];
        ptrs[a * 20001 + idx] = v;
        cur[a * 20001 + idx] = v;
    }
}
// u16 payloads: node ids < 20000 fit u16; per-class list = 256KB -> fits L2
__global__ void csrfill(const int* __restrict__ edges, int* __restrict__ cur,
                        u16* __restrict__ othercol, u16* __restrict__ otherrow)
{
    int gid = swz3584(blockIdx.x) * 256 + threadIdx.x;
    int i = gid >> 17, e = gid & (NEDGE - 1);
    const int* eb = edges + (size_t)i * 2 * NEDGE;
    int r = eb[e], c = eb[NEDGE + e];
    int pc = atomicAdd(&cur[i * 20001 + c], 1);
    othercol[(size_t)i * NEDGE + pc] = (u16)r;
    int pr = atomicAdd(&cur[(7 + i) * 20001 + r], 1);
    otherrow[(size_t)i * NEDGE + pr] = (u16)c;
}
// dinv from by-col degree (+1 self loop); degf = by-row degree (float)
__global__ void mkdinv(const int* __restrict__ ptrs, float* __restrict__ dinv,
                       float* __restrict__ degf)
{
    int gid = blockIdx.x * blockDim.x + threadIdx.x;
    if (gid >= NCLS * NNODES) return;
    int i = gid / NNODES, n = gid - i * NNODES;
    int d = ptrs[i * 20001 + n + 1] - ptrs[i * 20001 + n];
    dinv[gid] = rsqrtf((float)d + 1.0f);
    int dr = ptrs[(7 + i) * 20001 + n + 1] - ptrs[(7 + i) * 20001 + n];
    degf[gid] = (float)dr;
}

// ---------------------------------------------------------------------------
// BatchNorm apply (stats already accumulated by gemm_fn)
// ---------------------------------------------------------------------------
__global__ void bn_relu_b(const u16* __restrict__ xwb, const float* __restrict__ stats,
                          const float* __restrict__ gamma, const float* __restrict__ beta,
                          u16* __restrict__ tb)
{
    const int z = blockIdx.y;
    const int gid = blockIdx.x * blockDim.x + threadIdx.x;
    const int n = gid >> 6, f4 = (gid & 63) * 4;
    const u16* X = xwb + (size_t)z * NNODES * HID;
    u16* T = tb + (size_t)z * NNODES * HID;
    const float* st = stats + z * 2 * HID;
    const float invN = 1.0f / NNODES;
    float4 su = *(const float4*)&st[f4];
    float4 sq = *(const float4*)&st[HID + f4];
    float4 g  = *(const float4*)&gamma[(size_t)z * HID + f4];
    float4 be = *(const float4*)&beta[(size_t)z * HID + f4];
    ushort4 u = *(const ushort4*)&X[(size_t)n * HID + f4];
    float4 x = b2f4(u);
    float o[4], mu, var;
    mu = su.x * invN; var = sq.x * invN - mu * mu;
    o[0] = fmaxf((x.x - mu) * rsqrtf(var + BN_EPS) * g.x + be.x, 0.f);
    mu = su.y * invN; var = sq.y * invN - mu * mu;
    o[1] = fmaxf((x.y - mu) * rsqrtf(var + BN_EPS) * g.y + be.y, 0.f);
    mu = su.z * invN; var = sq.z * invN - mu * mu;
    o[2] = fmaxf((x.z - mu) * rsqrtf(var + BN_EPS) * g.z + be.z, 0.f);
    mu = su.w * invN; var = sq.w * invN - mu * mu;
    o[3] = fmaxf((x.w - mu) * rsqrtf(var + BN_EPS) * g.w + be.w, 0.f);
    *(ushort4*)&T[(size_t)n * HID + f4] = f2b4(o[0], o[1], o[2], o[3]);
}

// ---------------------------------------------------------------------------
// Fused dual gather, full-row, WAVE-PER-NODE (no intra-wave divergence),
// with x4 software-pipelined edge loops (4 independent 512B row loads in
// flight). Block = 256 thr = 4 nodes x 64 lanes (lane = 4 feats, 256 feats).
//   u[n] = dinv[n] * ( dinv[n]*t[n] + sum_{by-col} dinv[r]*t[r] )
//   v[n] = t[n] * sum_{by-row} t[c]
// ---------------------------------------------------------------------------
__global__ void gather2_u4(const u16* __restrict__ tb,
                           const int* __restrict__ cptrs, const u16* __restrict__ coth,
                           const int* __restrict__ rptrs, const u16* __restrict__ roth,
                           const float* __restrict__ dinv,
                           u16* __restrict__ ub, u16* __restrict__ vb, int nwg)
{
    const int logical = chunk_swz(blockIdx.x, nwg);
    const int z = logical / 5000, nb = logical % 5000;
    const size_t zo = (size_t)z * NNODES;
    const u16* T = tb + zo * HID;
    const int* cptr = cptrs + (size_t)z * 20001;
    const int* rptr = rptrs + (size_t)z * 20001;
    const u16* co = coth + (size_t)z * NEDGE;
    const u16* ro = roth + (size_t)z * NEDGE;
    const float* dv = dinv + zo;

    const int node = nb * 4 + (threadIdx.x >> 6);
    const int f = (threadIdx.x & 63) * 4;
    const float dn = dv[node];
    ushort4 tn = *(const ushort4*)&T[(size_t)node * HID + f];
    const float tnx = b2f(tn.x), tny = b2f(tn.y), tnz = b2f(tn.z), tnw = b2f(tn.w);

    // ---- u: by-col weighted aggregation (x4 pipelined, short tail) ----
    float ax = dn * tnx, ay = dn * tny, az = dn * tnz, aw = dn * tnw;
    {
        const int s0 = cptr[node], s1 = cptr[node + 1];
        int e = s0;
        for (; e + 4 <= s1; e += 4) {
            int r0 = co[e], r1 = co[e + 1], r2 = co[e + 2], r3 = co[e + 3];
            float d0 = dv[r0], d1 = dv[r1], d2 = dv[r2], d3 = dv[r3];
            ushort4 u0 = *(const ushort4*)&T[(size_t)r0 * HID + f];
            ushort4 u1 = *(const ushort4*)&T[(size_t)r1 * HID + f];
            ushort4 u2 = *(const ushort4*)&T[(size_t)r2 * HID + f];
            ushort4 u3 = *(const ushort4*)&T[(size_t)r3 * HID + f];
            ax += d0 * b2f(u0.x) + d1 * b2f(u1.x) + d2 * b2f(u2.x) + d3 * b2f(u3.x);
            ay += d0 * b2f(u0.y) + d1 * b2f(u1.y) + d2 * b2f(u2.y) + d3 * b2f(u3.y);
            az += d0 * b2f(u0.z) + d1 * b2f(u1.z) + d2 * b2f(u2.z) + d3 * b2f(u3.z);
            aw += d0 * b2f(u0.w) + d1 * b2f(u1.w) + d2 * b2f(u2.w) + d3 * b2f(u3.w);
        }
        for (; e < s1; ++e) {
            int r = co[e];
            float dr = dv[r];
            ushort4 u = *(const ushort4*)&T[(size_t)r * HID + f];
            ax += dr * b2f(u.x); ay += dr * b2f(u.y);
            az += dr * b2f(u.z); aw += dr * b2f(u.w);
        }
    }
    *(ushort4*)&ub[(zo + node) * HID + f] = f2b4(dn * ax, dn * ay, dn * az, dn * aw);

    // ---- v: by-row plain aggregation, times own features (x4 pipelined) ----
    float bx = 0.f, by = 0.f, bz = 0.f, bw = 0.f;
    {
        const int s0 = rptr[node], s1 = rptr[node + 1];
        int e = s0;
        for (; e + 4 <= s1; e += 4) {
            int r0 = ro[e], r1 = ro[e + 1], r2 = ro[e + 2], r3 = ro[e + 3];
            ushort4 u0 = *(const ushort4*)&T[(size_t)r0 * HID + f];
            ushort4 u1 = *(const ushort4*)&T[(size_t)r1 * HID + f];
            ushort4 u2 = *(const ushort4*)&T[(size_t)r2 * HID + f];
            ushort4 u3 = *(const ushort4*)&T[(size_t)r3 * HID + f];
            bx += b2f(u0.x) + b2f(u1.x) + b2f(u2.x) + b2f(u3.x);
            by += b2f(u0.y) + b2f(u1.y) + b2f(u2.y) + b2f(u3.y);
            bz += b2f(u0.z) + b2f(u1.z) + b2f(u2.z) + b2f(u3.z);
            bw += b2f(u0.w) + b2f(u1.w) + b2f(u2.w) + b2f(u3.w);
        }
        for (; e < s1; ++e) {
            int cc = ro[e];
            ushort4 u = *(const ushort4*)&T[(size_t)cc * HID + f];
            bx += b2f(u.x); by += b2f(u.y);
            bz += b2f(u.z); bw += b2f(u.w);
        }
    }
    *(ushort4*)&vb[(zo + node) * HID + f] = f2b4(tnx * bx, tny * by, tnz * bz, tnw * bw);
}

__global__ void final_cls(const float* __restrict__ outs, const float* __restrict__ clsW,
                          const float* __restrict__ clsb, float* __restrict__ out)
{
    const int gid = blockIdx.x * blockDim.x + threadIdx.x;
    if (gid >= NPAIR * NCLS) return;
    const int b = gid / NCLS, c = gid % NCLS;
    float acc = clsb[c];
    const float* row = outs + (size_t)b * 112;
    #pragma unroll 4
    for (int k = 0; k < 112; ++k)
        acc = fmaf(fmaxf(row[k], 0.f), clsW[k * NCLS + c], acc);
    out[gid] = acc;
}

// ---------------------------------------------------------------------------
extern "C" void kernel_launch(void* const* d_in, const int* in_sizes, int n_in,
                              void* d_out, int out_size, void* d_ws, size_t ws_size,
                              hipStream_t stream)
{
    const float* x        = (const float*)d_in[0];
    const int*   edges    = (const int*)  d_in[1];
    const int*   node_id  = (const int*)  d_in[2];
    const float* lin0_W   = (const float*)d_in[3];
    const float* lin0_b   = (const float*)d_in[4];
    const float* bn_gamma = (const float*)d_in[5];
    const float* bn_beta  = (const float*)d_in[6];
    const float* gcn_W    = (const float*)d_in[7];
    const float* gcn_b    = (const float*)d_in[8];
    const float* dp_W     = (const float*)d_in[9];
    const float* dp_b     = (const float*)d_in[10];
    const float* fc1_W    = (const float*)d_in[11];
    const float* fc1_b    = (const float*)d_in[12];
    const float* fc2_W    = (const float*)d_in[13];
    const float* fc2_b    = (const float*)d_in[14];
    const float* fc3_W    = (const float*)d_in[15];
    const float* fc3_b    = (const float*)d_in[16];
    const float* cls_W    = (const float*)d_in[17];
    const float* cls_b    = (const float*)d_in[18];
    float* out = (float*)d_out;

    unsigned char* w = (unsigned char*)d_ws;
    size_t used = 0;
    auto alloc = [&](size_t bytes) {
        void* p = (void*)(w + used);
        used += (bytes + 255) & ~(size_t)255;
        return p;
    };
    u16*   xb       = (u16*)  alloc((size_t)MPAD * DIN * 2);
    u16*   lin0Wt   = (u16*)  alloc((size_t)NCLS * HID * DIN * 2);
    u16*   gcnWt    = (u16*)  alloc((size_t)NCLS * NLAY * HID * HID * 2);
    u16*   dpWt     = (u16*)  alloc((size_t)NCLS * NLAY * HID * HID * 2);
    u16*   fc1Wt    = (u16*)  alloc((size_t)NCLS * 384 * 768 * 2);
    u16*   fc2Wt    = (u16*)  alloc((size_t)NCLS * 256 * 384 * 2);
    int*   ptrs     = (int*)  alloc((size_t)14 * 20001 * 4);
    int*   cur      = (int*)  alloc((size_t)14 * 20001 * 4);
    int*   aux      = (int*)  alloc((size_t)14 * 40 * 4);
    u16*   othercol = (u16*)  alloc((size_t)NCLS * NEDGE * 2);
    u16*   otherrow = (u16*)  alloc((size_t)NCLS * NEDGE * 2);
    float* dinv     = (float*)alloc((size_t)NCLS * NNODES * 4);
    float* degf     = (float*)alloc((size_t)NCLS * NNODES * 4);
    float* outsb    = (float*)alloc((size_t)NPAIR * 112 * 4);
    float* stats    = (float*)alloc((size_t)NCLS * 2 * HID * 4);

    // class-group size g: 3 big activation buffers (dual output aliases U)
    int g = 1;
    for (int t = NCLS; t >= 1; --t) {
        size_t big = ((size_t)t * NNODES + 96) * HID * 2;
        big = (big + 255) & ~(size_t)255;
        if (used + 3 * big <= ws_size) { g = t; break; }
    }
    size_t bigBytes = ((size_t)g * NNODES + 96) * HID * 2;
    u16* tbA  = (u16*)alloc(bigBytes);
    u16* ubuf = (u16*)alloc(bigBytes);
    u16* vbuf = (u16*)alloc(bigBytes);
    u16*   p1b = ubuf;           // head stage reuse
    float* p2f = (float*)vbuf;   // head stage reuse

    const int* src = node_id;
    const int* dst = node_id + NPAIR;

    // ---- setup ----
    xconv<<<(MPAD * DIN / 4) / 256, 256, 0, stream>>>(x, xb);
    wtrans<<<dim3(16, 8, 7),  256, 0, stream>>>(lin0_W, lin0Wt, 512, 256, 256);
    wtrans<<<dim3(8, 8, 14),  256, 0, stream>>>(gcn_W,  gcnWt,  256, 256, 256);
    wtrans<<<dim3(8, 8, 14),  256, 0, stream>>>(dp_W,   dpWt,   256, 256, 256);
    wtrans<<<dim3(24, 12, 7), 256, 0, stream>>>(fc1_W,  fc1Wt,  768, 384, 384);
    wtrans<<<dim3(12, 6, 7),  256, 0, stream>>>(fc2_W,  fc2Wt,  384, 192, 256);

    hipMemsetAsync(ptrs, 0, (size_t)14 * 20001 * 4, stream);
    hist<<<(NCLS * NEDGE) / 256, 256, 0, stream>>>(edges, ptrs);
    scan1<<<dim3(40, 14), SCN, 0, stream>>>(ptrs, aux);
    scan2<<<14, 64, 0, stream>>>(aux);
    scan3<<<dim3(40, 14), SCN, 0, stream>>>(ptrs, aux, cur);
    csrfill<<<(NCLS * NEDGE) / 256, 256, 0, stream>>>(edges, cur, othercol, otherrow);
    mkdinv<<<(NCLS * NNODES + 255) / 256, 256, 0, stream>>>(ptrs, dinv, degf);

    const size_t sT = (size_t)NNODES * HID;

    for (int cb = 0; cb < NCLS; cb += g) {
        const int gl = min(g, NCLS - cb);
        const int nwg = gl * 5000;   // 4 nodes/block, 5000 blocks/class

        // lin0 (A shared, fused colstats) -> ubuf ; BN+ReLU -> tbA
        hipMemsetAsync(stats, 0, (size_t)gl * 2 * HID * 4, stream);
        gemm_fn<<<dim3(157, 1, gl), 256, 0, stream>>>(
            xb, 0, lin0Wt + (size_t)cb * HID * DIN, (size_t)HID * DIN,
            lin0_b + cb * HID, HID, nullptr, ubuf, sT, NNODES, HID, DIN, 0, stats);
        bn_relu_b<<<dim3(5000, gl), 256, 0, stream>>>(
            ubuf, stats, bn_gamma + cb * HID, bn_beta + cb * HID, tbA);

        u16* t_cur = tbA;
        u16* t_alt = ubuf;
        for (int j = 0; j < NLAY; ++j) {
            const u16* gWt = gcnWt + ((size_t)cb * NLAY + j) * HID * HID;
            const u16* dWt = dpWt  + ((size_t)cb * NLAY + j) * HID * HID;
            const float* gb = gcn_b + ((size_t)cb * NLAY + j) * HID;
            const float* db = dp_b  + ((size_t)cb * NLAY + j) * HID;

            gather2_u4<<<nwg, 256, 0, stream>>>(
                t_cur, ptrs + cb * 20001, othercol + (size_t)cb * NEDGE,
                ptrs + (7 + cb) * 20001, otherrow + (size_t)cb * NEDGE,
                dinv + (size_t)cb * NNODES, t_alt, vbuf, nwg);
            gemm_dual<<<dim3(157, 1, gl), 256, 0, stream>>>(
                t_alt, vbuf, sT, gWt, dWt, (size_t)NLAY * HID * HID,
                gb, db, NLAY * HID, degf + (size_t)cb * NNODES, (size_t)NNODES,
                t_alt, NNODES);

            u16* tmp = t_cur; t_cur = t_alt; t_alt = tmp;
        }
        // after even NLAY, t_cur == tbA ; ubuf/vbuf free

        fc1_fused<<<dim3(64, 3, gl), 256, 0, stream>>>(
            t_cur, src, dst, fc1Wt + (size_t)cb * 384 * 768, fc1_b + cb * 384, p1b);
        gemm_fn<<<dim3(64, 1, gl), 256, 0, stream>>>(
            p1b, (size_t)NPAIR * 384, fc2Wt + (size_t)cb * 256 * 384, (size_t)256 * 384,
            fc2_b + cb * 192, 192, p2f, nullptr, (size_t)NPAIR * 192,
            NPAIR, 192, 384, 1, nullptr);
        gemm_bias_b<<<dim3(128, 1, gl), 256, 0, stream>>>(
            p2f, (size_t)NPAIR * 192, fc3_W + (size_t)cb * 192 * 16, (size_t)192 * 16,
            fc3_b + cb * 16, 16, outsb + cb * 16, 16,
            NPAIR, 16, 192, 112, 0);
    }

    final_cls<<<(NPAIR * NCLS + 255) / 256, 256, 0, stream>>>(outsb, cls_W, cls_b, out);
}